// Round 8
// baseline (763.093 us; speedup 1.0000x reference)
//
#include <hip/hip_runtime.h>
#include <math.h>

// KDC Lindblad propagator — real-basis reduction + fp64 MFMA + sparse Horner.
// f64 16x16x4 C/D layout (HW-probed round 4): col=lane&15, row=(lane>>4)+4*reg.
//
// Round 24 deltas on the round-23 skeleton (637.7 us):
//  (a) apply_T v4: 2x2 output-row grouping. r23 model: apply reads
//      sum K_p x 8KB = 131 MB at 10.3 TB/s = the L3/fabric ceiling (row
//      gather is inherently cross-XCD). Block (a,b) computes 4 rows
//      (2a+di, 2b+dj); list entries carry one row + 4 weights (loop-1 rows
//      shared across di, loop-2 across dj) -> ~48 unique rows/4 outputs vs
//      64 -> traffic ~-27%. Zero-weights keep per-output nonzero order ->
//      sums bitwise-preserved up to +0.0. a<b all-upper, a>b all-lower,
//      a==b per-output enumeration. Appendix: g iff a<8&&b<8; diag iff
//      (a>=8)+(b>=8)>0.
//  (b) ypart v2: internal 4x k-tile loop (grid y 16->4): scratch partials
//      16->4, yreduce reads 4x less.
//  dgemm FROZEN (r20 cfg + depth-2 prefetch; 46.9 us; 5 restructures tried).
// Pipeline: W = Taylor10(tau*T/16); U = W^16 (4 sq); U^2..U^32 (5 sq) with
// Y-doubling off chain intermediates; z_j = (U^32)^j x0 j=1..31; pops.

#define DS 1024
#define MATD ((size_t)DS * DS * sizeof(double))
#define PA 66

typedef double v4d __attribute__((ext_vector_type(4)));

__device__ inline double Qel(int i, int j) {
    if (i == j + 1) return sqrt((double)i) * 0.70710678118654752440;
    if (j == i + 1) return sqrt((double)j) * 0.70710678118654752440;
    return 0.0;
}

__device__ inline void fill_H(double* Hs, int tid) {
    const double CM2EV = 0.00012398419;
    const double E_S1 = 3.995, E_S2 = 4.9183;
    const double om6a = 596.0 * CM2EV, om10a = 919.0 * CM2EV;
    const double kapA = -0.0964, kapB = 0.1193, lam = 0.1825, gam = -0.018;
    for (int h = tid; h < 1024; h += 256) {
        int r = h >> 5, c = h & 31;
        int e = r >> 4, v6 = (r >> 2) & 3, v10 = r & 3;
        int e2 = c >> 4, w6 = (c >> 2) & 3, w10 = c & 3;
        double val = 0.0;
        if (r == c) val += (e ? E_S2 : E_S1) + om6a * v6 + om10a * v10;
        if (e == e2 && v10 == w10) val += (e ? kapB : kapA) * Qel(v6, w6);
        if (e != e2 && v6 == w6) {
            double q2 = 0.0;
            #pragma unroll
            for (int m = 0; m < 4; ++m) q2 += Qel(v10, m) * Qel(m, w10);
            val += lam * Qel(v10, w10) + gam * q2;
        }
        Hs[h] = val;
    }
}

// ------------------------------------------------ build G10 (+ Y/Z init) ----
__global__ __launch_bounds__(256)
void build_G10(const float* __restrict__ logg, double* __restrict__ X,
               double* __restrict__ Y, double* __restrict__ Z)
{
    int tid = threadIdx.x;
    if (blockIdx.x >= 4096) {
        int idx = (blockIdx.x - 4096) * 256 + tid;
        if (idx < 64 * 1024) {
            int r = idx >> 10, i = idx & 1023;
            double v = 0.0;
            if (r < 2 && i % 33 == 0) {
                int a = i / 33;
                if ((a < 16) == (r == 0)) v = 1.0;
            }
            Y[idx] = v;
        } else if (idx < 64 * 1024 + 1024) {
            int i = idx - 64 * 1024;
            Z[i] = (i == 528) ? 1.0 : 0.0;
        }
        return;
    }
    __shared__ double Hs[1024];
    fill_H(Hs, tid);
    __syncthreads();
    double g = exp((double)logg[0]);
    const double sc = ((1.0 / 0.6582119569) / 16.0) / 10.0;
    int idx = blockIdx.x * 256 + tid;
    int r = idx >> 10, c = idx & 1023;
    int i = r >> 5, j = r & 31;
    int k = c >> 5, l = c & 31;
    double t = 0.0;
    if (k <= l) {
        if (i <= j) {
            if (i < 16 && j < 16) {
                int p = i + 16, q = j + 16;
                if ((p == k && q == l) || (p == l && q == k)) t += g;
            }
            if (i == k && j == l) t -= 0.5 * g * ((i >= 16) + (j >= 16));
        } else {
            if (j == l) t += Hs[i * 32 + k];
            if (k != l && j == k) t += Hs[i * 32 + l];
            if (i == k) t -= Hs[l * 32 + j];
            if (k != l && i == l) t -= Hs[k * 32 + j];
        }
    } else {
        if (i <= j) {
            double ha = 0.0;
            if (j == l) ha += Hs[i * 32 + k];
            if (j == k) ha -= Hs[i * 32 + l];
            if (i == k) ha -= Hs[l * 32 + j];
            if (i == l) ha += Hs[k * 32 + j];
            t -= ha;
        } else {
            if (i < 16 && j < 16 && (i + 16 == k) && (j + 16 == l)) t += g;
            if (i == k && j == l) t -= 0.5 * g * ((i >= 16) + (j >= 16));
        }
    }
    X[idx] = t * sc + ((r == c) ? 1.0 : 0.0);
}

// --------------------------------------------------------- sparse T-apply ---
// O = I + sck * (T @ M). v4: block (a,b) computes the 4 output rows
// (2a+di, 2b+dj). List entries: (q, w0..w3) — one row read feeds 4
// accumulators. a<b: all rows upper-branch; a>b: all lower; a==b: per-row.
// Candidate waves: off-diag {F1 jsel=j0, F1 jsel=j1, F2 isel=i0, F2
// isel=i1} x m; diag: wave = output r, fam = lane>>5. Ballot-compacted.
__global__ __launch_bounds__(256)
void apply_T(const float* __restrict__ logg, const double* __restrict__ M,
             double* __restrict__ O, double invk)
{
    __shared__ double Hs[1024];
    __shared__ int    qlist[112];
    __shared__ double wl[4][112];
    __shared__ int    counts[4];
    __shared__ int    Kshared;
    const int tid = threadIdx.x;
    fill_H(Hs, tid);
    __syncthreads();
    const double g = exp((double)logg[0]);
    const double sck = ((1.0 / 0.6582119569) / 16.0) * invk;

    const int a = blockIdx.x >> 4, b = blockIdx.x & 15;
    const int i0 = a << 1, j0 = b << 1;
    const int wv = tid >> 6, lane = tid & 63;
    const int m = lane & 31;

    bool valid = false; int q = 0;
    double w0 = 0.0, w1 = 0.0, w2 = 0.0, w3 = 0.0;

    if (a != b) {
        if (lane < 32) {
            const bool fam2 = (wv >= 2);
            const int sel = wv & 1;
            if (!fam2) {                       // F1: rows (m ∨ jsel), H[i*][m]
                const int js = j0 + sel;
                double cA = Hs[i0 * 32 + m];
                double cB = Hs[(i0 + 1) * 32 + m];
                if (a < b) {                   // upper
                    if ((cA != 0.0 || cB != 0.0) && m != js) {
                        valid = true;
                        q = (m > js) ? m * 32 + js : js * 32 + m;
                        double sA = (m > js) ? -cA : cA;
                        double sB = (m > js) ? -cB : cB;
                        if (sel == 0) { w0 = sA; w2 = sB; }
                        else          { w1 = sA; w3 = sB; }
                    }
                } else {                       // lower
                    if (cA != 0.0 || cB != 0.0) {
                        valid = true;
                        q = (m < js) ? m * 32 + js : js * 32 + m;
                        if (sel == 0) { w0 = cA; w2 = cB; }
                        else          { w1 = cA; w3 = cB; }
                    }
                }
            } else {                           // F2: rows (m ∨ isel), H[m][j*]
                const int is = i0 + sel;
                double c0 = Hs[m * 32 + j0];
                double c1 = Hs[m * 32 + j0 + 1];
                if (a < b) {                   // upper
                    if ((c0 != 0.0 || c1 != 0.0) && m != is) {
                        valid = true;
                        q = (is > m) ? is * 32 + m : m * 32 + is;
                        double s0 = (is > m) ? c0 : -c0;
                        double s1 = (is > m) ? c1 : -c1;
                        if (sel == 0) { w0 = s0; w1 = s1; }
                        else          { w2 = s0; w3 = s1; }
                    }
                } else {                       // lower
                    if (c0 != 0.0 || c1 != 0.0) {
                        valid = true;
                        q = (m < is) ? m * 32 + is : is * 32 + m;
                        if (sel == 0) { w0 = -c0; w1 = -c1; }
                        else          { w2 = -c0; w3 = -c1; }
                    }
                }
            }
        }
    } else {
        // diagonal block: wave wv = output r; lane: fam = lane>>5, m
        const int ia = i0 + (wv >> 1), ja = j0 + (wv & 1);
        const bool up = (ia <= ja);
        double wr = 0.0;
        if (lane < 32) {                       // loop1: c = H[ia][m]
            double c = Hs[ia * 32 + m];
            if (up) {
                if (c != 0.0 && m != ja) {
                    valid = true;
                    q = (m > ja) ? m * 32 + ja : ja * 32 + m;
                    wr = (m > ja) ? -c : c;
                }
            } else {
                if (c != 0.0) {
                    valid = true;
                    q = (m < ja) ? m * 32 + ja : ja * 32 + m;
                    wr = c;
                }
            }
        } else {                               // loop2: c = H[m][ja]
            double c = Hs[m * 32 + ja];
            if (up) {
                if (c != 0.0 && m != ia) {
                    valid = true;
                    q = (ia > m) ? ia * 32 + m : m * 32 + ia;
                    wr = (ia > m) ? c : -c;
                }
            } else {
                if (c != 0.0) {
                    valid = true;
                    q = (m < ia) ? m * 32 + ia : ia * 32 + m;
                    wr = -c;
                }
            }
        }
        if (wv == 0) w0 = wr; else if (wv == 1) w1 = wr;
        else if (wv == 2) w2 = wr; else w3 = wr;
    }

    unsigned long long mask = __ballot(valid);
    if (lane == 0) counts[wv] = __popcll(mask);
    __syncthreads();
    int base = 0;
    for (int t = 0; t < wv; ++t) base += counts[t];
    if (valid) {
        int slot = base + __popcll(mask & ((1ull << lane) - 1ull));
        qlist[slot] = q;
        wl[0][slot] = w0; wl[1][slot] = w1; wl[2][slot] = w2; wl[3][slot] = w3;
    }
    __syncthreads();
    if (tid == 0) {
        int K = counts[0] + counts[1] + counts[2] + counts[3];
        const int cnt = (a >= 8) + (b >= 8);
        if (a < 8 && b < 8) {
            #pragma unroll
            for (int r = 0; r < 4; ++r) {
                int ia = i0 + (r >> 1), ja = j0 + (r & 1);
                qlist[K] = (ia + 16) * 32 + (ja + 16);
                wl[0][K] = 0.0; wl[1][K] = 0.0; wl[2][K] = 0.0; wl[3][K] = 0.0;
                wl[r][K] = g; ++K;
            }
        }
        if (cnt > 0) {
            double wd = -0.5 * g * (double)cnt;
            #pragma unroll
            for (int r = 0; r < 4; ++r) {
                int ia = i0 + (r >> 1), ja = j0 + (r & 1);
                qlist[K] = ia * 32 + ja;
                wl[0][K] = 0.0; wl[1][K] = 0.0; wl[2][K] = 0.0; wl[3][K] = 0.0;
                wl[r][K] = wd; ++K;
            }
        }
        while (K & 1) {
            qlist[K] = 0;
            wl[0][K] = 0.0; wl[1][K] = 0.0; wl[2][K] = 0.0; wl[3][K] = 0.0;
            ++K;
        }
        Kshared = K;
    }
    __syncthreads();
    const int K = Kshared;

    double acc[4][4];
    #pragma unroll
    for (int r = 0; r < 4; ++r)
        #pragma unroll
        for (int u = 0; u < 4; ++u) acc[r][u] = 0.0;

    const double2* Mp = (const double2*)M;
    const int e2 = tid << 1;                 // double2 index of col 4*tid
    for (int k = 0; k < K; k += 2) {
        #pragma unroll
        for (int u = 0; u < 2; ++u) {
            int qq = qlist[k + u];
            double W0 = wl[0][k + u], W1 = wl[1][k + u];
            double W2 = wl[2][k + u], W3 = wl[3][k + u];
            double2 v0 = Mp[(size_t)qq * (DS / 2) + e2];
            double2 v1 = Mp[(size_t)qq * (DS / 2) + e2 + 1];
            acc[0][0] += W0 * v0.x; acc[0][1] += W0 * v0.y;
            acc[0][2] += W0 * v1.x; acc[0][3] += W0 * v1.y;
            acc[1][0] += W1 * v0.x; acc[1][1] += W1 * v0.y;
            acc[1][2] += W1 * v1.x; acc[1][3] += W1 * v1.y;
            acc[2][0] += W2 * v0.x; acc[2][1] += W2 * v0.y;
            acc[2][2] += W2 * v1.x; acc[2][3] += W2 * v1.y;
            acc[3][0] += W3 * v0.x; acc[3][1] += W3 * v0.y;
            acc[3][2] += W3 * v1.x; acc[3][3] += W3 * v1.y;
        }
    }

    const int c0 = tid << 2;
    #pragma unroll
    for (int r = 0; r < 4; ++r) {
        int pr = (i0 + (r >> 1)) * 32 + (j0 + (r & 1));
        size_t bse = (size_t)pr * DS + c0;
        O[bse + 0] = sck * acc[r][0] + ((pr == c0)     ? 1.0 : 0.0);
        O[bse + 1] = sck * acc[r][1] + ((pr == c0 + 1) ? 1.0 : 0.0);
        O[bse + 2] = sck * acc[r][2] + ((pr == c0 + 2) ? 1.0 : 0.0);
        O[bse + 3] = sck * acc[r][3] + ((pr == c0 + 3) ? 1.0 : 0.0);
    }
}

// --------------------------------------------------------- dgemm (MFMA f64) -
// D = A*B. 64x64 tile, 1024 threads (16 waves): 4 output quadrants x 4
// k-groups (k-split-4 within KT=64); 3-phase reduction. LDS double-buffer,
// one barrier per kt, writes mid-iteration, depth-2 global prefetch.
// FROZEN (r20+r23 config, 46.9 us).
__global__ __launch_bounds__(1024, 1)
void dgemm(const double* __restrict__ A, const double* __restrict__ B,
           double* __restrict__ D)
{
    __shared__ double As[2][64 * PA];
    __shared__ double Bs[2][64 * PA];
    const int tid = threadIdx.x;
    const int bm = blockIdx.x << 6, bn = blockIdx.y << 6;
    const int w = tid >> 6, lane = tid & 63;
    const int lr = lane & 15, lk = lane >> 4;
    const int p = w & 3, kg = w >> 2;
    const int wr = (p >> 1) << 5, wc = (p & 1) << 5;

    v4d acc[2][2];
    #pragma unroll
    for (int si = 0; si < 2; ++si)
        #pragma unroll
        for (int sj = 0; sj < 2; ++sj) acc[si][sj] = (v4d){0., 0., 0., 0.};

    const int ra = tid >> 4;
    const int cs = (tid & 15) << 2;
    const double* gA = A + (size_t)(bm + ra) * DS + cs;
    const double* gB = B + (size_t)ra * DS + bn + cs;
    double va[4], vb[4];
    #pragma unroll
    for (int u = 0; u < 4; ++u) { va[u] = gA[u]; vb[u] = gB[u]; }
    #pragma unroll
    for (int u = 0; u < 4; ++u) {
        As[0][ra * PA + cs + u] = va[u];
        Bs[0][ra * PA + cs + u] = vb[u];
    }
    // depth-2 prefetch: tile 1 (kt=64) into registers now
    #pragma unroll
    for (int u = 0; u < 4; ++u) {
        va[u] = gA[64 + u];
        vb[u] = gB[(size_t)64 * DS + u];
    }
    __syncthreads();

    #pragma unroll 2
    for (int kt = 0; kt < DS; kt += 64) {
        const int pb = (kt >> 6) & 1;
        const bool more  = (kt + 64) < DS;
        const bool more2 = (kt + 128) < DS;
        const int k0 = (kg << 4) + lk;
        double A00 = As[pb][(wr + lr) * PA + k0];
        double A10 = As[pb][(wr + 16 + lr) * PA + k0];
        double B00 = Bs[pb][k0 * PA + wc + lr];
        double B10 = Bs[pb][k0 * PA + wc + 16 + lr];
        double A01 = As[pb][(wr + lr) * PA + k0 + 4];
        double A11 = As[pb][(wr + 16 + lr) * PA + k0 + 4];
        double B01 = Bs[pb][(k0 + 4) * PA + wc + lr];
        double B11 = Bs[pb][(k0 + 4) * PA + wc + 16 + lr];
        acc[0][0] = __builtin_amdgcn_mfma_f64_16x16x4f64(A00, B00, acc[0][0], 0, 0, 0);
        acc[0][1] = __builtin_amdgcn_mfma_f64_16x16x4f64(A00, B10, acc[0][1], 0, 0, 0);
        acc[1][0] = __builtin_amdgcn_mfma_f64_16x16x4f64(A10, B00, acc[1][0], 0, 0, 0);
        acc[1][1] = __builtin_amdgcn_mfma_f64_16x16x4f64(A10, B10, acc[1][1], 0, 0, 0);
        acc[0][0] = __builtin_amdgcn_mfma_f64_16x16x4f64(A01, B01, acc[0][0], 0, 0, 0);
        acc[0][1] = __builtin_amdgcn_mfma_f64_16x16x4f64(A01, B11, acc[0][1], 0, 0, 0);
        acc[1][0] = __builtin_amdgcn_mfma_f64_16x16x4f64(A11, B01, acc[1][0], 0, 0, 0);
        acc[1][1] = __builtin_amdgcn_mfma_f64_16x16x4f64(A11, B11, acc[1][1], 0, 0, 0);
        if (more) {
            #pragma unroll
            for (int u = 0; u < 4; ++u) {
                As[pb ^ 1][ra * PA + cs + u] = va[u];
                Bs[pb ^ 1][ra * PA + cs + u] = vb[u];
            }
        }
        if (more2) {
            #pragma unroll
            for (int u = 0; u < 4; ++u) {
                va[u] = gA[kt + 128 + u];
                vb[u] = gB[(size_t)(kt + 128) * DS + u];
            }
        }
        double A02 = As[pb][(wr + lr) * PA + k0 + 8];
        double A12 = As[pb][(wr + 16 + lr) * PA + k0 + 8];
        double B02 = Bs[pb][(k0 + 8) * PA + wc + lr];
        double B12 = Bs[pb][(k0 + 8) * PA + wc + 16 + lr];
        double A03 = As[pb][(wr + lr) * PA + k0 + 12];
        double A13 = As[pb][(wr + 16 + lr) * PA + k0 + 12];
        double B03 = Bs[pb][(k0 + 12) * PA + wc + lr];
        double B13 = Bs[pb][(k0 + 12) * PA + wc + 16 + lr];
        acc[0][0] = __builtin_amdgcn_mfma_f64_16x16x4f64(A02, B02, acc[0][0], 0, 0, 0);
        acc[0][1] = __builtin_amdgcn_mfma_f64_16x16x4f64(A02, B12, acc[0][1], 0, 0, 0);
        acc[1][0] = __builtin_amdgcn_mfma_f64_16x16x4f64(A12, B02, acc[1][0], 0, 0, 0);
        acc[1][1] = __builtin_amdgcn_mfma_f64_16x16x4f64(A12, B12, acc[1][1], 0, 0, 0);
        acc[0][0] = __builtin_amdgcn_mfma_f64_16x16x4f64(A03, B03, acc[0][0], 0, 0, 0);
        acc[0][1] = __builtin_amdgcn_mfma_f64_16x16x4f64(A03, B13, acc[0][1], 0, 0, 0);
        acc[1][0] = __builtin_amdgcn_mfma_f64_16x16x4f64(A13, B03, acc[1][0], 0, 0, 0);
        acc[1][1] = __builtin_amdgcn_mfma_f64_16x16x4f64(A13, B13, acc[1][1], 0, 0, 0);
        __syncthreads();
    }

    double* red = &As[0][0];
    if (kg == 3) {
        #pragma unroll
        for (int si = 0; si < 2; ++si)
            #pragma unroll
            for (int sj = 0; sj < 2; ++sj)
                #pragma unroll
                for (int r = 0; r < 4; ++r)
                    red[(wr + si * 16 + lk + 4 * r) * 64 + wc + sj * 16 + lr]
                        = acc[si][sj][r];
    }
    __syncthreads();
    if (kg == 2) {
        #pragma unroll
        for (int si = 0; si < 2; ++si)
            #pragma unroll
            for (int sj = 0; sj < 2; ++sj)
                #pragma unroll
                for (int r = 0; r < 4; ++r)
                    red[(wr + si * 16 + lk + 4 * r) * 64 + wc + sj * 16 + lr]
                        += acc[si][sj][r];
    }
    __syncthreads();
    if (kg == 1) {
        #pragma unroll
        for (int si = 0; si < 2; ++si)
            #pragma unroll
            for (int sj = 0; sj < 2; ++sj)
                #pragma unroll
                for (int r = 0; r < 4; ++r)
                    red[(wr + si * 16 + lk + 4 * r) * 64 + wc + sj * 16 + lr]
                        += acc[si][sj][r];
    }
    __syncthreads();
    if (kg == 0) {
        #pragma unroll
        for (int si = 0; si < 2; ++si)
            #pragma unroll
            for (int sj = 0; sj < 2; ++sj) {
                int col = bn + wc + sj * 16 + lr;
                #pragma unroll
                for (int r = 0; r < 4; ++r) {
                    int row = bm + wr + si * 16 + lk + 4 * r;
                    D[(size_t)row * DS + col] = acc[si][sj][r]
                        + red[(wr + si * 16 + lk + 4 * r) * 64 + wc + sj * 16 + lr];
                }
            }
    }
}

// --------------------------------------------------------- ypart ------------
// v2: each block walks 4 k-tiles internally (grid y = 4) -> scratch
// partials 16 -> 4, yreduce traffic / 4.
__global__ __launch_bounds__(256)
void ypart(const double* __restrict__ P, const double* __restrict__ Y,
           double* __restrict__ scratch, int SR)
{
    __shared__ double Yld[32 * 64];
    __shared__ double red[32 * 64];
    const int tid = threadIdx.x;
    const int cc = tid & 63, kw = tid >> 6;
    const int col = (blockIdx.x << 6) + cc;
    const int r0 = blockIdx.z << 5;

    double acc[32];
    #pragma unroll
    for (int r = 0; r < 32; ++r) acc[r] = 0.0;

    for (int kt = 0; kt < 4; ++kt) {
        const int kb = ((blockIdx.y << 2) + kt) << 6;
        __syncthreads();
        for (int idx = tid; idx < 32 * 64; idx += 256) {
            int r = idx >> 6, kk = idx & 63;
            Yld[idx] = Y[(size_t)(r0 + r) * DS + kb + kk];
        }
        __syncthreads();
        #pragma unroll
        for (int kk = 0; kk < 16; ++kk) {
            int kl = (kw << 4) + kk;
            double pv = P[(size_t)(kb + kl) * DS + col];
            #pragma unroll
            for (int r = 0; r < 32; ++r)
                acc[r] += Yld[(r << 6) + kl] * pv;
        }
    }

    __syncthreads();
    if (kw == 3) {
        #pragma unroll
        for (int r = 0; r < 32; ++r) red[(r << 6) + cc] = acc[r];
    }
    __syncthreads();
    if (kw == 2) {
        #pragma unroll
        for (int r = 0; r < 32; ++r) red[(r << 6) + cc] += acc[r];
    }
    __syncthreads();
    if (kw == 1) {
        #pragma unroll
        for (int r = 0; r < 32; ++r) red[(r << 6) + cc] += acc[r];
    }
    __syncthreads();
    if (kw == 0) {
        #pragma unroll
        for (int r = 0; r < 32; ++r) red[(r << 6) + cc] += acc[r];
    }
    __syncthreads();
    for (int idx = tid; idx < 32 * 64; idx += 256) {
        int r = idx >> 6, c2 = idx & 63;
        scratch[((size_t)blockIdx.y * SR + r0 + r) * DS + (blockIdx.x << 6) + c2]
            = red[idx];
    }
}

// --------------------------------------------------------- yreduce ----------
__global__ __launch_bounds__(256)
void yreduce(const double* __restrict__ scratch, double* __restrict__ Y,
             int M, int SR)
{
    int idx = blockIdx.x * 256 + threadIdx.x;
    int r = idx >> 10, c = idx & 1023;
    double s = 0.0;
    #pragma unroll
    for (int q = 0; q < 4; ++q)
        s += scratch[((size_t)q * SR + r) * DS + c];
    Y[(size_t)(M + r) * DS + c] = s;
}

// --------------------------------------------------------- Z matvec ---------
__global__ __launch_bounds__(256)
void zstep(const double* __restrict__ V, const double* __restrict__ Zin,
           double* __restrict__ Zout)
{
    int row = blockIdx.x * 4 + (threadIdx.x >> 6);
    int lane = threadIdx.x & 63;
    const double2* r_ = (const double2*)(V + (size_t)row * DS);
    const double2* z_ = (const double2*)Zin;
    double s = 0.0;
    #pragma unroll
    for (int k = 0; k < 8; ++k) {
        double2 a = r_[(k << 6) + lane];
        double2 b = z_[(k << 6) + lane];
        s += a.x * b.x + a.y * b.y;
    }
    #pragma unroll
    for (int off = 32; off; off >>= 1) s += __shfl_down(s, off);
    if (lane == 0) Zout[row] = s;
}

// --------------------------------------------------------- output -----------
// t = a + 32 j; y = Y row (2a+k); z = Z[j].
__global__ __launch_bounds__(128)
void final_pops(const double* __restrict__ Y, const double* __restrict__ Z,
                float* __restrict__ out, int n)
{
    int t = blockIdx.x;
    int k = threadIdx.x >> 6, lane = threadIdx.x & 63;
    int a = t & 31, j = t >> 5;
    const double* y = Y + (size_t)(2 * a + k) * 1024;
    const double* z = Z + (size_t)j * 1024;
    double s = 0.0;
    for (int i = lane; i < 1024; i += 64) s += y[i] * z[i];
    #pragma unroll
    for (int off = 32; off; off >>= 1) s += __shfl_down(s, off);
    if (lane == 0) {
        out[(size_t)(k + 1) * n + t] = (float)s;
        if (k == 0) out[t] = 0.0f;
    }
}

// --------------------------------------------------------- host -------------
static inline void ydouble2(const double* P, double* Y, double* scr, int M,
                            hipStream_t stream)
{
    int gz = (M + 31) / 32; if (gz < 1) gz = 1;
    int SR = gz * 32;
    ypart<<<dim3(16, 4, gz), 256, 0, stream>>>(P, Y, scr, SR);
    yreduce<<<SR * 4, 256, 0, stream>>>(scr, Y, M, SR);
}

extern "C" void kernel_launch(void* const* d_in, const int* in_sizes, int n_in,
                              void* d_out, int out_size, void* d_ws, size_t ws_size,
                              hipStream_t stream)
{
    const float* logg = (const float*)d_in[0];
    float* out = (float*)d_out;
    const int n = out_size / 3;
    (void)in_sizes; (void)n_in; (void)ws_size;

    char* ws = (char*)d_ws;
    double* b0 = (double*)(ws + 0 * MATD);
    double* b1 = (double*)(ws + 1 * MATD);
    double* b2 = (double*)(ws + 2 * MATD);
    double* scr = (double*)(ws + 3 * MATD);  // 4 x 32 x 1024 (1 MB)
    double* Y  = (double*)(ws + 5 * MATD);   // 64 rows x 1024 (512 KB)
    double* Z  = Y + 64 * 1024;              // 32 x 1024

    dim3 g2(16, 16);

    // ---- W = Taylor10(tau*T/16): G10 dense (+Y/Z init), 9 sparse applies --
    build_G10<<<4096 + 260, 256, 0, stream>>>(logg, b0, Y, Z);
    double* src = b0; double* dst = b1;
    for (int k = 9; k >= 1; --k) {
        apply_T<<<256, 256, 0, stream>>>(logg, src, dst, 1.0 / (double)k);
        double* t = src; src = dst; dst = t;
    }
    // 9 applies (odd) -> W in b1

    // ---- squarings interleaved with Y-doubling (9 dgemms total) ----
    dgemm<<<g2, 1024, 0, stream>>>(b1, b1, b0);   // W^2
    dgemm<<<g2, 1024, 0, stream>>>(b0, b0, b2);   // W^4
    dgemm<<<g2, 1024, 0, stream>>>(b2, b2, b1);   // W^8
    dgemm<<<g2, 1024, 0, stream>>>(b1, b1, b0);   // U = W^16
    ydouble2(b0, Y, scr, 2, stream);              // a += 1   (U)
    dgemm<<<g2, 1024, 0, stream>>>(b0, b0, b1);   // U^2
    ydouble2(b1, Y, scr, 4, stream);              // a += 2
    dgemm<<<g2, 1024, 0, stream>>>(b1, b1, b2);   // U^4
    ydouble2(b2, Y, scr, 8, stream);              // a += 4
    dgemm<<<g2, 1024, 0, stream>>>(b2, b2, b1);   // U^8
    ydouble2(b1, Y, scr, 16, stream);             // a += 8
    dgemm<<<g2, 1024, 0, stream>>>(b1, b1, b2);   // U^16
    ydouble2(b2, Y, scr, 32, stream);             // a += 16
    dgemm<<<g2, 1024, 0, stream>>>(b2, b2, b1);   // U^32

    // ---- Z chain: z_j = (U^32)^j x0, j = 1..31 ----
    for (int j = 1; j < 32; ++j)
        zstep<<<256, 256, 0, stream>>>(b1, Z + (size_t)(j - 1) * 1024,
                                       Z + (size_t)j * 1024);

    final_pops<<<n, 128, 0, stream>>>(Y, Z, out, n);
}

// Round 9
// 635.385 us; speedup vs baseline: 1.2010x; 1.2010x over previous
//
#include <hip/hip_runtime.h>
#include <math.h>

// KDC Lindblad propagator — real-basis reduction + fp64 MFMA + sparse Horner.
// f64 16x16x4 C/D layout (HW-probed round 4): col=lane&15, row=(lane>>4)+4*reg.
//
// Round 25 = pure REVERT to the round-23 kernel (637.7 us measured).
// r24's apply_T 2x2 grouping + ypart k-loop both regressed (+125 us):
// both cut grid size 4x (apply_T 1024->256 blocks = 4 waves/CU) and the
// L3-latency-bound gather lost its latency hiding — occupancy, not
// traffic, is the binding resource for these kernels. Lesson recorded;
// apply_T/ypart revert to their r23 forms (1024 blocks / grid-y 16).
//  dgemm FROZEN (r20 cfg + depth-2 prefetch).
// Pipeline: W = Taylor10(tau*T/16); U = W^16 (4 sq); U^2..U^32 (5 sq) with
// Y-doubling off chain intermediates; z_j = (U^32)^j x0 j=1..31; pops.

#define DS 1024
#define MATD ((size_t)DS * DS * sizeof(double))
#define PA 66

typedef double v4d __attribute__((ext_vector_type(4)));

__device__ inline double Qel(int i, int j) {
    if (i == j + 1) return sqrt((double)i) * 0.70710678118654752440;
    if (j == i + 1) return sqrt((double)j) * 0.70710678118654752440;
    return 0.0;
}

__device__ inline void fill_H(double* Hs, int tid) {
    const double CM2EV = 0.00012398419;
    const double E_S1 = 3.995, E_S2 = 4.9183;
    const double om6a = 596.0 * CM2EV, om10a = 919.0 * CM2EV;
    const double kapA = -0.0964, kapB = 0.1193, lam = 0.1825, gam = -0.018;
    for (int h = tid; h < 1024; h += 256) {
        int r = h >> 5, c = h & 31;
        int e = r >> 4, v6 = (r >> 2) & 3, v10 = r & 3;
        int e2 = c >> 4, w6 = (c >> 2) & 3, w10 = c & 3;
        double val = 0.0;
        if (r == c) val += (e ? E_S2 : E_S1) + om6a * v6 + om10a * v10;
        if (e == e2 && v10 == w10) val += (e ? kapB : kapA) * Qel(v6, w6);
        if (e != e2 && v6 == w6) {
            double q2 = 0.0;
            #pragma unroll
            for (int m = 0; m < 4; ++m) q2 += Qel(v10, m) * Qel(m, w10);
            val += lam * Qel(v10, w10) + gam * q2;
        }
        Hs[h] = val;
    }
}

// ------------------------------------------------ build G10 (+ Y/Z init) ----
__global__ __launch_bounds__(256)
void build_G10(const float* __restrict__ logg, double* __restrict__ X,
               double* __restrict__ Y, double* __restrict__ Z)
{
    int tid = threadIdx.x;
    if (blockIdx.x >= 4096) {
        int idx = (blockIdx.x - 4096) * 256 + tid;
        if (idx < 64 * 1024) {
            int r = idx >> 10, i = idx & 1023;
            double v = 0.0;
            if (r < 2 && i % 33 == 0) {
                int a = i / 33;
                if ((a < 16) == (r == 0)) v = 1.0;
            }
            Y[idx] = v;
        } else if (idx < 64 * 1024 + 1024) {
            int i = idx - 64 * 1024;
            Z[i] = (i == 528) ? 1.0 : 0.0;
        }
        return;
    }
    __shared__ double Hs[1024];
    fill_H(Hs, tid);
    __syncthreads();
    double g = exp((double)logg[0]);
    const double sc = ((1.0 / 0.6582119569) / 16.0) / 10.0;
    int idx = blockIdx.x * 256 + tid;
    int r = idx >> 10, c = idx & 1023;
    int i = r >> 5, j = r & 31;
    int k = c >> 5, l = c & 31;
    double t = 0.0;
    if (k <= l) {
        if (i <= j) {
            if (i < 16 && j < 16) {
                int p = i + 16, q = j + 16;
                if ((p == k && q == l) || (p == l && q == k)) t += g;
            }
            if (i == k && j == l) t -= 0.5 * g * ((i >= 16) + (j >= 16));
        } else {
            if (j == l) t += Hs[i * 32 + k];
            if (k != l && j == k) t += Hs[i * 32 + l];
            if (i == k) t -= Hs[l * 32 + j];
            if (k != l && i == l) t -= Hs[k * 32 + j];
        }
    } else {
        if (i <= j) {
            double ha = 0.0;
            if (j == l) ha += Hs[i * 32 + k];
            if (j == k) ha -= Hs[i * 32 + l];
            if (i == k) ha -= Hs[l * 32 + j];
            if (i == l) ha += Hs[k * 32 + j];
            t -= ha;
        } else {
            if (i < 16 && j < 16 && (i + 16 == k) && (j + 16 == l)) t += g;
            if (i == k && j == l) t -= 0.5 * g * ((i >= 16) + (j >= 16));
        }
    }
    X[idx] = t * sc + ((r == c) ? 1.0 : 0.0);
}

// --------------------------------------------------------- sparse T-apply ---
// O = I + sck * (T @ M). Two-phase: wave 0 builds the (q, w) list in
// original loop order (ballot prefix-sum -> bitwise-identical accumulation),
// then all threads run a branch-free unroll-4 loop with b128 loads.
__global__ __launch_bounds__(256)
void apply_T(const float* __restrict__ logg, const double* __restrict__ M,
             double* __restrict__ O, double invk)
{
    __shared__ double Hs[1024];
    __shared__ double wlist[72];
    __shared__ int    qlist[72];
    __shared__ int    Kshared;
    const int tid = threadIdx.x;
    fill_H(Hs, tid);
    __syncthreads();
    const double g = exp((double)logg[0]);
    const double sck = ((1.0 / 0.6582119569) / 16.0) * invk;
    const int p = ((blockIdx.x & 7) << 7) | (blockIdx.x >> 3);   // XCD chunk
    const int i = p >> 5, j = p & 31;

    if (tid < 64) {
        const int m = tid & 31;
        const bool loop2 = tid >= 32;
        double c = loop2 ? Hs[m * 32 + j] : Hs[i * 32 + m];
        int q = 0; double w = 0.0; bool valid;
        if (i <= j) {
            if (!loop2) {
                valid = (c != 0.0) && (m != j);
                q = (m > j) ? m * 32 + j : j * 32 + m;
                w = (m > j) ? -c : c;
            } else {
                valid = (c != 0.0) && (m != i);
                q = (i > m) ? i * 32 + m : m * 32 + i;
                w = (i > m) ? c : -c;
            }
        } else {
            if (!loop2) {
                valid = (c != 0.0);
                int lo = m < j ? m : j, hi = m < j ? j : m;
                q = lo * 32 + hi; w = c;
            } else {
                valid = (c != 0.0);
                int lo = m < i ? m : i, hi = m < i ? i : m;
                q = lo * 32 + hi; w = -c;
            }
        }
        unsigned long long mask = __ballot(valid);
        int slot = __popcll(mask & ((1ull << tid) - 1ull));
        if (valid) { qlist[slot] = q; wlist[slot] = w; }
        if (tid == 0) {
            int K = __popcll(mask);
            if (i < 16 && j < 16) {
                qlist[K] = (i + 16) * 32 + (j + 16); wlist[K] = g; ++K;
            }
            double wd = -0.5 * g * (double)((i >= 16) + (j >= 16));
            if (wd != 0.0) { qlist[K] = p; wlist[K] = wd; ++K; }
            while (K & 3) { qlist[K] = 0; wlist[K] = 0.0; ++K; }
            Kshared = K;
        }
    }
    __syncthreads();
    const int K = Kshared;

    double a0 = 0.0, a1 = 0.0, a2 = 0.0, a3 = 0.0;
    const double2* Mp = (const double2*)M;
    const int e2 = tid << 1;                 // double2 index of col 4*tid
    for (int k = 0; k < K; k += 4) {
        #pragma unroll
        for (int u = 0; u < 4; ++u) {
            int q = qlist[k + u];
            double w = wlist[k + u];
            double2 v0 = Mp[(size_t)q * (DS / 2) + e2];
            double2 v1 = Mp[(size_t)q * (DS / 2) + e2 + 1];
            a0 += w * v0.x; a1 += w * v0.y;
            a2 += w * v1.x; a3 += w * v1.y;
        }
    }
    const int c0 = tid << 2;
    size_t base = (size_t)p * DS + c0;
    O[base + 0] = sck * a0 + ((p == c0)     ? 1.0 : 0.0);
    O[base + 1] = sck * a1 + ((p == c0 + 1) ? 1.0 : 0.0);
    O[base + 2] = sck * a2 + ((p == c0 + 2) ? 1.0 : 0.0);
    O[base + 3] = sck * a3 + ((p == c0 + 3) ? 1.0 : 0.0);
}

// --------------------------------------------------------- dgemm (MFMA f64) -
// D = A*B. 64x64 tile, 1024 threads (16 waves): 4 output quadrants x 4
// k-groups (k-split-4 within KT=64); 3-phase reduction. LDS double-buffer,
// one barrier per kt, writes mid-iteration, depth-2 global prefetch.
// FROZEN (r20+r23 config).
__global__ __launch_bounds__(1024, 1)
void dgemm(const double* __restrict__ A, const double* __restrict__ B,
           double* __restrict__ D)
{
    __shared__ double As[2][64 * PA];
    __shared__ double Bs[2][64 * PA];
    const int tid = threadIdx.x;
    const int bm = blockIdx.x << 6, bn = blockIdx.y << 6;
    const int w = tid >> 6, lane = tid & 63;
    const int lr = lane & 15, lk = lane >> 4;
    const int p = w & 3, kg = w >> 2;
    const int wr = (p >> 1) << 5, wc = (p & 1) << 5;

    v4d acc[2][2];
    #pragma unroll
    for (int si = 0; si < 2; ++si)
        #pragma unroll
        for (int sj = 0; sj < 2; ++sj) acc[si][sj] = (v4d){0., 0., 0., 0.};

    const int ra = tid >> 4;
    const int cs = (tid & 15) << 2;
    const double* gA = A + (size_t)(bm + ra) * DS + cs;
    const double* gB = B + (size_t)ra * DS + bn + cs;
    double va[4], vb[4];
    #pragma unroll
    for (int u = 0; u < 4; ++u) { va[u] = gA[u]; vb[u] = gB[u]; }
    #pragma unroll
    for (int u = 0; u < 4; ++u) {
        As[0][ra * PA + cs + u] = va[u];
        Bs[0][ra * PA + cs + u] = vb[u];
    }
    // depth-2 prefetch: tile 1 (kt=64) into registers now
    #pragma unroll
    for (int u = 0; u < 4; ++u) {
        va[u] = gA[64 + u];
        vb[u] = gB[(size_t)64 * DS + u];
    }
    __syncthreads();

    #pragma unroll 2
    for (int kt = 0; kt < DS; kt += 64) {
        const int pb = (kt >> 6) & 1;
        const bool more  = (kt + 64) < DS;
        const bool more2 = (kt + 128) < DS;
        const int k0 = (kg << 4) + lk;
        double A00 = As[pb][(wr + lr) * PA + k0];
        double A10 = As[pb][(wr + 16 + lr) * PA + k0];
        double B00 = Bs[pb][k0 * PA + wc + lr];
        double B10 = Bs[pb][k0 * PA + wc + 16 + lr];
        double A01 = As[pb][(wr + lr) * PA + k0 + 4];
        double A11 = As[pb][(wr + 16 + lr) * PA + k0 + 4];
        double B01 = Bs[pb][(k0 + 4) * PA + wc + lr];
        double B11 = Bs[pb][(k0 + 4) * PA + wc + 16 + lr];
        acc[0][0] = __builtin_amdgcn_mfma_f64_16x16x4f64(A00, B00, acc[0][0], 0, 0, 0);
        acc[0][1] = __builtin_amdgcn_mfma_f64_16x16x4f64(A00, B10, acc[0][1], 0, 0, 0);
        acc[1][0] = __builtin_amdgcn_mfma_f64_16x16x4f64(A10, B00, acc[1][0], 0, 0, 0);
        acc[1][1] = __builtin_amdgcn_mfma_f64_16x16x4f64(A10, B10, acc[1][1], 0, 0, 0);
        acc[0][0] = __builtin_amdgcn_mfma_f64_16x16x4f64(A01, B01, acc[0][0], 0, 0, 0);
        acc[0][1] = __builtin_amdgcn_mfma_f64_16x16x4f64(A01, B11, acc[0][1], 0, 0, 0);
        acc[1][0] = __builtin_amdgcn_mfma_f64_16x16x4f64(A11, B01, acc[1][0], 0, 0, 0);
        acc[1][1] = __builtin_amdgcn_mfma_f64_16x16x4f64(A11, B11, acc[1][1], 0, 0, 0);
        if (more) {
            #pragma unroll
            for (int u = 0; u < 4; ++u) {
                As[pb ^ 1][ra * PA + cs + u] = va[u];
                Bs[pb ^ 1][ra * PA + cs + u] = vb[u];
            }
        }
        if (more2) {
            #pragma unroll
            for (int u = 0; u < 4; ++u) {
                va[u] = gA[kt + 128 + u];
                vb[u] = gB[(size_t)(kt + 128) * DS + u];
            }
        }
        double A02 = As[pb][(wr + lr) * PA + k0 + 8];
        double A12 = As[pb][(wr + 16 + lr) * PA + k0 + 8];
        double B02 = Bs[pb][(k0 + 8) * PA + wc + lr];
        double B12 = Bs[pb][(k0 + 8) * PA + wc + 16 + lr];
        double A03 = As[pb][(wr + lr) * PA + k0 + 12];
        double A13 = As[pb][(wr + 16 + lr) * PA + k0 + 12];
        double B03 = Bs[pb][(k0 + 12) * PA + wc + lr];
        double B13 = Bs[pb][(k0 + 12) * PA + wc + 16 + lr];
        acc[0][0] = __builtin_amdgcn_mfma_f64_16x16x4f64(A02, B02, acc[0][0], 0, 0, 0);
        acc[0][1] = __builtin_amdgcn_mfma_f64_16x16x4f64(A02, B12, acc[0][1], 0, 0, 0);
        acc[1][0] = __builtin_amdgcn_mfma_f64_16x16x4f64(A12, B02, acc[1][0], 0, 0, 0);
        acc[1][1] = __builtin_amdgcn_mfma_f64_16x16x4f64(A12, B12, acc[1][1], 0, 0, 0);
        acc[0][0] = __builtin_amdgcn_mfma_f64_16x16x4f64(A03, B03, acc[0][0], 0, 0, 0);
        acc[0][1] = __builtin_amdgcn_mfma_f64_16x16x4f64(A03, B13, acc[0][1], 0, 0, 0);
        acc[1][0] = __builtin_amdgcn_mfma_f64_16x16x4f64(A13, B03, acc[1][0], 0, 0, 0);
        acc[1][1] = __builtin_amdgcn_mfma_f64_16x16x4f64(A13, B13, acc[1][1], 0, 0, 0);
        __syncthreads();
    }

    double* red = &As[0][0];
    if (kg == 3) {
        #pragma unroll
        for (int si = 0; si < 2; ++si)
            #pragma unroll
            for (int sj = 0; sj < 2; ++sj)
                #pragma unroll
                for (int r = 0; r < 4; ++r)
                    red[(wr + si * 16 + lk + 4 * r) * 64 + wc + sj * 16 + lr]
                        = acc[si][sj][r];
    }
    __syncthreads();
    if (kg == 2) {
        #pragma unroll
        for (int si = 0; si < 2; ++si)
            #pragma unroll
            for (int sj = 0; sj < 2; ++sj)
                #pragma unroll
                for (int r = 0; r < 4; ++r)
                    red[(wr + si * 16 + lk + 4 * r) * 64 + wc + sj * 16 + lr]
                        += acc[si][sj][r];
    }
    __syncthreads();
    if (kg == 1) {
        #pragma unroll
        for (int si = 0; si < 2; ++si)
            #pragma unroll
            for (int sj = 0; sj < 2; ++sj)
                #pragma unroll
                for (int r = 0; r < 4; ++r)
                    red[(wr + si * 16 + lk + 4 * r) * 64 + wc + sj * 16 + lr]
                        += acc[si][sj][r];
    }
    __syncthreads();
    if (kg == 0) {
        #pragma unroll
        for (int si = 0; si < 2; ++si)
            #pragma unroll
            for (int sj = 0; sj < 2; ++sj) {
                int col = bn + wc + sj * 16 + lr;
                #pragma unroll
                for (int r = 0; r < 4; ++r) {
                    int row = bm + wr + si * 16 + lk + 4 * r;
                    D[(size_t)row * DS + col] = acc[si][sj][r]
                        + red[(wr + si * 16 + lk + 4 * r) * 64 + wc + sj * 16 + lr];
                }
            }
    }
}

// --------------------------------------------------------- ypart ------------
__global__ __launch_bounds__(256)
void ypart(const double* __restrict__ P, const double* __restrict__ Y,
           double* __restrict__ scratch, int SR)
{
    __shared__ double Yld[32 * 64];
    __shared__ double red[32 * 64];
    const int tid = threadIdx.x;
    const int cc = tid & 63, kw = tid >> 6;
    const int col = (blockIdx.x << 6) + cc;
    const int kb = blockIdx.y << 6;
    const int r0 = blockIdx.z << 5;

    for (int idx = tid; idx < 32 * 64; idx += 256) {
        int r = idx >> 6, kk = idx & 63;
        Yld[idx] = Y[(size_t)(r0 + r) * DS + kb + kk];
    }
    __syncthreads();

    double acc[32];
    #pragma unroll
    for (int r = 0; r < 32; ++r) acc[r] = 0.0;

    #pragma unroll
    for (int kk = 0; kk < 16; ++kk) {
        int kl = (kw << 4) + kk;
        double pv = P[(size_t)(kb + kl) * DS + col];
        #pragma unroll
        for (int r = 0; r < 32; ++r)
            acc[r] += Yld[(r << 6) + kl] * pv;
    }

    __syncthreads();
    if (kw == 3) {
        #pragma unroll
        for (int r = 0; r < 32; ++r) red[(r << 6) + cc] = acc[r];
    }
    __syncthreads();
    if (kw == 2) {
        #pragma unroll
        for (int r = 0; r < 32; ++r) red[(r << 6) + cc] += acc[r];
    }
    __syncthreads();
    if (kw == 1) {
        #pragma unroll
        for (int r = 0; r < 32; ++r) red[(r << 6) + cc] += acc[r];
    }
    __syncthreads();
    if (kw == 0) {
        #pragma unroll
        for (int r = 0; r < 32; ++r) red[(r << 6) + cc] += acc[r];
    }
    __syncthreads();
    for (int idx = tid; idx < 32 * 64; idx += 256) {
        int r = idx >> 6, c2 = idx & 63;
        scratch[((size_t)blockIdx.y * SR + r0 + r) * DS + (blockIdx.x << 6) + c2]
            = red[idx];
    }
}

// --------------------------------------------------------- yreduce ----------
__global__ __launch_bounds__(256)
void yreduce(const double* __restrict__ scratch, double* __restrict__ Y,
             int M, int SR)
{
    int idx = blockIdx.x * 256 + threadIdx.x;
    int r = idx >> 10, c = idx & 1023;
    double s = 0.0;
    #pragma unroll
    for (int q = 0; q < 16; ++q)
        s += scratch[((size_t)q * SR + r) * DS + c];
    Y[(size_t)(M + r) * DS + c] = s;
}

// --------------------------------------------------------- Z matvec ---------
__global__ __launch_bounds__(256)
void zstep(const double* __restrict__ V, const double* __restrict__ Zin,
           double* __restrict__ Zout)
{
    int row = blockIdx.x * 4 + (threadIdx.x >> 6);
    int lane = threadIdx.x & 63;
    const double2* r_ = (const double2*)(V + (size_t)row * DS);
    const double2* z_ = (const double2*)Zin;
    double s = 0.0;
    #pragma unroll
    for (int k = 0; k < 8; ++k) {
        double2 a = r_[(k << 6) + lane];
        double2 b = z_[(k << 6) + lane];
        s += a.x * b.x + a.y * b.y;
    }
    #pragma unroll
    for (int off = 32; off; off >>= 1) s += __shfl_down(s, off);
    if (lane == 0) Zout[row] = s;
}

// --------------------------------------------------------- output -----------
// t = a + 32 j; y = Y row (2a+k); z = Z[j].
__global__ __launch_bounds__(128)
void final_pops(const double* __restrict__ Y, const double* __restrict__ Z,
                float* __restrict__ out, int n)
{
    int t = blockIdx.x;
    int k = threadIdx.x >> 6, lane = threadIdx.x & 63;
    int a = t & 31, j = t >> 5;
    const double* y = Y + (size_t)(2 * a + k) * 1024;
    const double* z = Z + (size_t)j * 1024;
    double s = 0.0;
    for (int i = lane; i < 1024; i += 64) s += y[i] * z[i];
    #pragma unroll
    for (int off = 32; off; off >>= 1) s += __shfl_down(s, off);
    if (lane == 0) {
        out[(size_t)(k + 1) * n + t] = (float)s;
        if (k == 0) out[t] = 0.0f;
    }
}

// --------------------------------------------------------- host -------------
static inline void ydouble2(const double* P, double* Y, double* scr, int M,
                            hipStream_t stream)
{
    int gz = (M + 31) / 32; if (gz < 1) gz = 1;
    int SR = gz * 32;
    ypart<<<dim3(16, 16, gz), 256, 0, stream>>>(P, Y, scr, SR);
    yreduce<<<SR * 4, 256, 0, stream>>>(scr, Y, M, SR);
}

extern "C" void kernel_launch(void* const* d_in, const int* in_sizes, int n_in,
                              void* d_out, int out_size, void* d_ws, size_t ws_size,
                              hipStream_t stream)
{
    const float* logg = (const float*)d_in[0];
    float* out = (float*)d_out;
    const int n = out_size / 3;
    (void)in_sizes; (void)n_in; (void)ws_size;

    char* ws = (char*)d_ws;
    double* b0 = (double*)(ws + 0 * MATD);
    double* b1 = (double*)(ws + 1 * MATD);
    double* b2 = (double*)(ws + 2 * MATD);
    double* scr = (double*)(ws + 3 * MATD);  // 16 x 32 x 1024 (4 MB)
    double* Y  = (double*)(ws + 5 * MATD);   // 64 rows x 1024 (512 KB)
    double* Z  = Y + 64 * 1024;              // 32 x 1024

    dim3 g2(16, 16);

    // ---- W = Taylor10(tau*T/16): G10 dense (+Y/Z init), 9 sparse applies --
    build_G10<<<4096 + 260, 256, 0, stream>>>(logg, b0, Y, Z);
    double* src = b0; double* dst = b1;
    for (int k = 9; k >= 1; --k) {
        apply_T<<<1024, 256, 0, stream>>>(logg, src, dst, 1.0 / (double)k);
        double* t = src; src = dst; dst = t;
    }
    // 9 applies (odd) -> W in b1

    // ---- squarings interleaved with Y-doubling (9 dgemms total) ----
    dgemm<<<g2, 1024, 0, stream>>>(b1, b1, b0);   // W^2
    dgemm<<<g2, 1024, 0, stream>>>(b0, b0, b2);   // W^4
    dgemm<<<g2, 1024, 0, stream>>>(b2, b2, b1);   // W^8
    dgemm<<<g2, 1024, 0, stream>>>(b1, b1, b0);   // U = W^16
    ydouble2(b0, Y, scr, 2, stream);              // a += 1   (U)
    dgemm<<<g2, 1024, 0, stream>>>(b0, b0, b1);   // U^2
    ydouble2(b1, Y, scr, 4, stream);              // a += 2
    dgemm<<<g2, 1024, 0, stream>>>(b1, b1, b2);   // U^4
    ydouble2(b2, Y, scr, 8, stream);              // a += 4
    dgemm<<<g2, 1024, 0, stream>>>(b2, b2, b1);   // U^8
    ydouble2(b1, Y, scr, 16, stream);             // a += 8
    dgemm<<<g2, 1024, 0, stream>>>(b1, b1, b2);   // U^16
    ydouble2(b2, Y, scr, 32, stream);             // a += 16
    dgemm<<<g2, 1024, 0, stream>>>(b2, b2, b1);   // U^32

    // ---- Z chain: z_j = (U^32)^j x0, j = 1..31 ----
    for (int j = 1; j < 32; ++j)
        zstep<<<256, 256, 0, stream>>>(b1, Z + (size_t)(j - 1) * 1024,
                                       Z + (size_t)j * 1024);

    final_pops<<<n, 128, 0, stream>>>(Y, Z, out, n);
}